// Round 5
// baseline (79.036 us; speedup 1.0000x reference)
//
#include <hip/hip_runtime.h>
#include <math.h>

#define BB 4
#define SS 4096
#define DD 256
#define WT_PLANE 65536  // shorts per W1 bf16 plane (256x256)

typedef __attribute__((ext_vector_type(8))) short bf8v;  // 8 bf16 (4 VGPRs)
typedef __attribute__((ext_vector_type(4))) float f4v;   // MFMA accumulator

// ---- bf16 helpers (RNE) ----
__device__ __forceinline__ ushort f2bf(float f) {
    uint u = __float_as_uint(f);
    u += 0x7fffu + ((u >> 16) & 1u);
    return (ushort)(u >> 16);
}
__device__ __forceinline__ float bf2f(ushort h) {
    return __uint_as_float(((uint)h) << 16);
}
// 3-way split of two floats, packed per plane: a = h + m + l (+ ~2^-27 rel)
__device__ __forceinline__ void split3two(float a, float b, uint& h, uint& m, uint& l) {
    const ushort ah = f2bf(a);
    const float ra = a - bf2f(ah);      // exact (Sterbenz)
    const ushort am_ = f2bf(ra);
    const float ra2 = ra - bf2f(am_);   // exact
    const ushort al_ = f2bf(ra2);
    const ushort bh = f2bf(b);
    const float rb = b - bf2f(bh);
    const ushort bm_ = f2bf(rb);
    const float rb2 = rb - bf2f(bm_);
    const ushort bl_ = f2bf(rb2);
    h = (uint)ah | ((uint)bh << 16);
    m = (uint)am_ | ((uint)bm_ << 16);
    l = (uint)al_ | ((uint)bl_ << 16);
}

// ---------------------------------------------------------------------------
// K0: W1 (fp32 [k][c]) -> 3 bf16 planes in MFMA-fragment-linear layout:
// short index = ((c>>4)*8 + (k>>5))*512 + ((k>>3)&3)*128 + (c&15)*8 + (k&7)
// so a wave's B-frag load for (ct,ks,plane) is one coalesced 1KB dwordx4.
// grid (4,4) of 64x64 tiles, 256 thr, LDS transpose.
// ---------------------------------------------------------------------------
__global__ __launch_bounds__(256) void convert_kernel(const float* __restrict__ W1,
                                                      ushort* __restrict__ wt) {
    __shared__ float tile[64][65];
    const int k0 = blockIdx.x * 64;
    const int c0 = blockIdx.y * 64;
    const int tid = threadIdx.x;
    {
        const int kr = tid >> 2;   // 64 k-rows
        const int cs = tid & 3;    // 16-col chunk
        const float* src = W1 + (size_t)(k0 + kr) * DD + c0 + cs * 16;
#pragma unroll
        for (int i = 0; i < 4; ++i) {
            const float4 v = *(const float4*)(src + i * 4);
            tile[kr][cs * 16 + i * 4 + 0] = v.x;
            tile[kr][cs * 16 + i * 4 + 1] = v.y;
            tile[kr][cs * 16 + i * 4 + 2] = v.z;
            tile[kr][cs * 16 + i * 4 + 3] = v.w;
        }
    }
    __syncthreads();
    {
        const int cr = tid >> 2;   // 64 cols
        const int ks2 = tid & 3;   // 16-k quarter (2 octets)
        const int c = c0 + cr;
#pragma unroll
        for (int oct = 0; oct < 2; ++oct) {
            const int k = k0 + ks2 * 16 + oct * 8;  // global k of octet start
            const int kl = ks2 * 16 + oct * 8;      // local k
            uint H[4], M[4], L[4];
#pragma unroll
            for (int i = 0; i < 4; ++i) {
                const float fa = tile[kl + 2 * i + 0][cr];
                const float fb = tile[kl + 2 * i + 1][cr];
                split3two(fa, fb, H[i], M[i], L[i]);
            }
            const size_t idx = ((size_t)(c >> 4) * 8 + (k >> 5)) * 512
                             + (size_t)((k >> 3) & 3) * 128 + (size_t)(c & 15) * 8;
            *(uint4*)(wt + idx) = make_uint4(H[0], H[1], H[2], H[3]);
            *(uint4*)(wt + WT_PLANE + idx) = make_uint4(M[0], M[1], M[2], M[3]);
            *(uint4*)(wt + 2 * WT_PLANE + idx) = make_uint4(L[0], L[1], L[2], L[3]);
        }
    }
}

// ---------------------------------------------------------------------------
// K1: q[b][h] = sum_i x[b,0,i] * W0[i,h]  (RoPE at pos 0 = identity)
// Also zeroes y (blocks with hc==0).
// ---------------------------------------------------------------------------
__global__ __launch_bounds__(256) void qkernel(const float* __restrict__ x,
                                               const float* __restrict__ W0,
                                               float* __restrict__ q,
                                               float* __restrict__ y) {
    const int b = blockIdx.x;
    const int hc = blockIdx.y;
    const int tid = threadIdx.x;
    if (hc == 0) y[b * DD + tid] = 0.f;
    const int hk = tid & 31;
    const int iseg = tid >> 5;
    const int h = hc * 32 + hk;
    const float* xrow = x + (size_t)b * SS * DD;
    float p = 0.f;
#pragma unroll
    for (int k = 0; k < 32; ++k) {
        const int i = iseg * 32 + k;
        p = fmaf(xrow[i], W0[i * DD + h], p);
    }
    __shared__ float red[256];
    red[tid] = p;
    __syncthreads();
    if (tid < 32) {
        float s = 0.f;
#pragma unroll
        for (int j = 0; j < 8; ++j) s += red[j * 32 + tid];
        q[b * DD + hc * 32 + tid] = s;
    }
}

// ---------------------------------------------------------------------------
// K2: scores[b][t] = q_b . R_t( x[b,t,:] @ W1 )  via 3-way-split 6-pass bf16
// MFMA (fp32-parity: per-product residual ~2^-27).
// grid 512 (4 b x 128 blocks of 32 rows), block 128 thr (2 waves, 16 rows ea).
// Stage: x tile fp32 -> 3 bf16 planes in LDS, XOR-swizzled 16B slots.
// Wave: 16 col-tiles of mfma_f32_16x16x32_bf16 over K=256 (8 ks steps),
// 6 passes per (ks,ct). B frags: coalesced dwordx4 from repacked wt.
// Epilogue: direct sincosf((float)t * expf(jj*kfac)) — bit-identical trig to
// the validated fp32 rounds — RoPE folded into dot with q, 16-lane reduce.
// ---------------------------------------------------------------------------
__global__ __launch_bounds__(128) void scores_mfma(const float* __restrict__ x,
                                                   const ushort* __restrict__ wt,
                                                   const float* __restrict__ q,
                                                   float* __restrict__ scores) {
    __shared__ __align__(16) ushort xs[3][32][256];  // 48 KB: 3 planes x 32 rows
    __shared__ float q_s[256];
    const int tid = threadIdx.x;
    const int bid = blockIdx.x;
    const int b = bid >> 7;
    const int row0 = (bid & 127) << 5;

    q_s[tid] = q[b * DD + tid];
    q_s[tid + 128] = q[b * DD + 128 + tid];

    // ---- stage: fp32 -> 3 bf16 planes, swizzled on 16B slots ----
    {
        const int r = tid & 31;    // row
        const int seg = tid >> 5;  // 64-k segment
        const float* xr = x + ((size_t)(b * SS + row0 + r)) * DD + seg * 64;
        char* ph = (char*)&xs[0][r][0];
        char* pm = (char*)&xs[1][r][0];
        char* pl = (char*)&xs[2][r][0];
        const int swz = (r & 15) << 4;
#pragma unroll
        for (int j = 0; j < 8; ++j) {
            const float4 fa = *(const float4*)(xr + j * 8);
            const float4 fb = *(const float4*)(xr + j * 8 + 4);
            uint H[4], M[4], L[4];
            split3two(fa.x, fa.y, H[0], M[0], L[0]);
            split3two(fa.z, fa.w, H[1], M[1], L[1]);
            split3two(fb.x, fb.y, H[2], M[2], L[2]);
            split3two(fb.z, fb.w, H[3], M[3], L[3]);
            const int off = (((seg * 8 + j) * 16) ^ swz);
            *(uint4*)(ph + off) = make_uint4(H[0], H[1], H[2], H[3]);
            *(uint4*)(pm + off) = make_uint4(M[0], M[1], M[2], M[3]);
            *(uint4*)(pl + off) = make_uint4(L[0], L[1], L[2], L[3]);
        }
    }
    __syncthreads();

    const int lane = tid & 63;
    const int wv = tid >> 6;     // wave id (0..1) -> 16-row half
    const int l15 = lane & 15;
    const int hg = lane >> 4;    // 0..3
    const int r0 = wv * 16;

    f4v acc[16];
#pragma unroll
    for (int ct = 0; ct < 16; ++ct) acc[ct] = {0.f, 0.f, 0.f, 0.f};

    const char* ah_base = (const char*)&xs[0][r0 + l15][0];
    const char* am_base = (const char*)&xs[1][r0 + l15][0];
    const char* al_base = (const char*)&xs[2][r0 + l15][0];
    const int aswz = l15 << 4;  // (row & 15) == l15
    const ushort* wb = wt + (size_t)lane * 8;  // lane-linear fragment base

#pragma unroll 2
    for (int ks = 0; ks < 8; ++ks) {
        const int aoff = (((ks * 4 + hg) * 16) ^ aswz);
        const bf8v a_h = *(const bf8v*)(ah_base + aoff);
        const bf8v a_m = *(const bf8v*)(am_base + aoff);
        const bf8v a_l = *(const bf8v*)(al_base + aoff);
#pragma unroll
        for (int ct = 0; ct < 16; ++ct) {
            const ushort* bp = wb + (size_t)(ct * 8 + ks) * 512;
            const bf8v b_h = *(const bf8v*)(bp);
            const bf8v b_m = *(const bf8v*)(bp + WT_PLANE);
            const bf8v b_l = *(const bf8v*)(bp + 2 * WT_PLANE);
            acc[ct] = __builtin_amdgcn_mfma_f32_16x16x32_bf16(a_h, b_h, acc[ct], 0, 0, 0);
            acc[ct] = __builtin_amdgcn_mfma_f32_16x16x32_bf16(a_h, b_m, acc[ct], 0, 0, 0);
            acc[ct] = __builtin_amdgcn_mfma_f32_16x16x32_bf16(a_m, b_h, acc[ct], 0, 0, 0);
            acc[ct] = __builtin_amdgcn_mfma_f32_16x16x32_bf16(a_h, b_l, acc[ct], 0, 0, 0);
            acc[ct] = __builtin_amdgcn_mfma_f32_16x16x32_bf16(a_m, b_m, acc[ct], 0, 0, 0);
            acc[ct] = __builtin_amdgcn_mfma_f32_16x16x32_bf16(a_l, b_h, acc[ct], 0, 0, 0);
        }
    }

    // ---- epilogue: RoPE-folded dot with q (direct trig, validated form) ----
    const float kfac = (float)(-9.210340371976184 / 128.0);  // -ln(1e4)/128
    const int par = l15 & 1;
    const int tr = row0 + r0 + hg * 4;  // first of this lane's 4 rows
    float p0 = 0.f, p1 = 0.f, p2 = 0.f, p3 = 0.f;
#pragma unroll
    for (int ct = 0; ct < 16; ++ct) {
        const int jj = ct * 8 + (l15 >> 1);
        const float d = expf((float)jj * kfac);
        const float qe = q_s[2 * jj], qo = q_s[2 * jj + 1];
        float sv, cv, u;
        sincosf((float)(tr + 0) * d, &sv, &cv);
        u = par ? (qo * cv - qe * sv) : (qe * cv + qo * sv);
        p0 = fmaf(acc[ct][0], u, p0);
        sincosf((float)(tr + 1) * d, &sv, &cv);
        u = par ? (qo * cv - qe * sv) : (qe * cv + qo * sv);
        p1 = fmaf(acc[ct][1], u, p1);
        sincosf((float)(tr + 2) * d, &sv, &cv);
        u = par ? (qo * cv - qe * sv) : (qe * cv + qo * sv);
        p2 = fmaf(acc[ct][2], u, p2);
        sincosf((float)(tr + 3) * d, &sv, &cv);
        u = par ? (qo * cv - qe * sv) : (qe * cv + qo * sv);
        p3 = fmaf(acc[ct][3], u, p3);
    }
#pragma unroll
    for (int off = 1; off <= 8; off <<= 1) {
        p0 += __shfl_xor(p0, off);
        p1 += __shfl_xor(p1, off);
        p2 += __shfl_xor(p2, off);
        p3 += __shfl_xor(p3, off);
    }
    if (l15 == 0) {
        float* dst = scores + (size_t)b * SS + tr;
        dst[0] = p0;
        dst[1] = p1;
        dst[2] = p2;
        dst[3] = p3;
    }
}

// ---------------------------------------------------------------------------
// K3: fused softmax + weighted row-sum (attn ~one-hot: skip exact zeros).
// ---------------------------------------------------------------------------
__global__ __launch_bounds__(256) void fused_kernel(const float* __restrict__ x,
                                                    const float* __restrict__ scores,
                                                    float* __restrict__ y) {
    const int c = blockIdx.x;
    const int b = blockIdx.y;
    const int tid = threadIdx.x;
    const int lane = tid & 63;
    const int wid = tid >> 6;
    const float* sb = scores + (size_t)b * SS;

    float4 v[4];
    float m = -INFINITY;
#pragma unroll
    for (int i = 0; i < 4; ++i) {
        v[i] = *(const float4*)(sb + tid * 16 + i * 4);
        m = fmaxf(m, fmaxf(fmaxf(v[i].x, v[i].y), fmaxf(v[i].z, v[i].w)));
    }
#pragma unroll
    for (int off = 32; off >= 1; off >>= 1) m = fmaxf(m, __shfl_xor(m, off));
    __shared__ float redm[4];
    __shared__ float reds[4];
    __shared__ float a_s[64];
    if (lane == 0) redm[wid] = m;
    __syncthreads();
    const float M = fmaxf(fmaxf(redm[0], redm[1]), fmaxf(redm[2], redm[3]));

    float s = 0.f;
#pragma unroll
    for (int i = 0; i < 4; ++i) {
        s += expf(v[i].x - M);
        s += expf(v[i].y - M);
        s += expf(v[i].z - M);
        s += expf(v[i].w - M);
    }
#pragma unroll
    for (int off = 32; off >= 1; off >>= 1) s += __shfl_xor(s, off);
    if (lane == 0) reds[wid] = s;
    __syncthreads();
    const float S = ((reds[0] + reds[1]) + reds[2]) + reds[3];
    const float inv = 1.0f / S;

    if (tid < 64) a_s[tid] = expf(sb[c * 64 + tid] - M) * inv;
    __syncthreads();

    float accv = 0.f;
    for (int t = 0; t < 64; ++t) {
        const float a = a_s[t];
        if (a != 0.f)
            accv = fmaf(a, x[((size_t)(b * SS + c * 64 + t)) * DD + tid], accv);
    }
    atomicAdd(&y[b * DD + tid], accv);
}

// ---------------------------------------------------------------------------
// K4: out[b][o] = sum_i y[b][i] * W2[i][o]. grid 4, block 256, direct write.
// ---------------------------------------------------------------------------
__global__ __launch_bounds__(256) void out_kernel(const float* __restrict__ y,
                                                  const float* __restrict__ W2,
                                                  float* __restrict__ out) {
    const int b = blockIdx.x;
    const int o = threadIdx.x;
    __shared__ float y_s[DD];
    y_s[o] = y[b * DD + o];
    __syncthreads();
    float p = 0.f;
#pragma unroll 8
    for (int i = 0; i < DD; ++i) p = fmaf(y_s[i], W2[(size_t)i * DD + o], p);
    out[b * DD + o] = p;
}

// ---------------------------------------------------------------------------
extern "C" void kernel_launch(void* const* d_in, const int* in_sizes, int n_in,
                              void* d_out, int out_size, void* d_ws, size_t ws_size,
                              hipStream_t stream) {
    const float* x = (const float*)d_in[0];
    const float* W0 = (const float*)d_in[1];
    const float* W1 = (const float*)d_in[2];
    const float* W2 = (const float*)d_in[3];
    float* ws = (float*)d_ws;
    float* q = ws;                      // 1024 floats
    float* scores = ws + 1024;          // 16384 floats
    float* y = ws + 1024 + 16384;       // 1024 floats
    ushort* wt = (ushort*)(ws + 18432); // 3 planes x 128 KB = 384 KB
    float* out = (float*)d_out;

    convert_kernel<<<dim3(4, 4), 256, 0, stream>>>(W1, wt);
    qkernel<<<dim3(BB, 8), 256, 0, stream>>>(x, W0, q, y);
    scores_mfma<<<dim3(512), 128, 0, stream>>>(x, wt, q, scores);
    fused_kernel<<<dim3(64, BB), 256, 0, stream>>>(x, scores, y);
    out_kernel<<<dim3(BB), 256, 0, stream>>>(y, W2, out);
}

// Round 6
// 37.383 us; speedup vs baseline: 2.1142x; 2.1142x over previous
//
#include <hip/hip_runtime.h>
#include <math.h>

#define BB 4
#define SS 4096
#define DD 256
#define WT_PLANE 65536  // shorts per W1 bf16 plane (256x256)

typedef __attribute__((ext_vector_type(8))) short bf8v;  // 8 bf16 (4 VGPRs)
typedef __attribute__((ext_vector_type(4))) float f4v;   // MFMA accumulator

// ---- bf16 helpers (RNE) ----
__device__ __forceinline__ ushort f2bf(float f) {
    uint u = __float_as_uint(f);
    u += 0x7fffu + ((u >> 16) & 1u);
    return (ushort)(u >> 16);
}
__device__ __forceinline__ float bf2f(ushort h) {
    return __uint_as_float(((uint)h) << 16);
}
// 3-way split of two floats, packed per plane: a = h + m + l (+ ~2^-27 rel)
__device__ __forceinline__ void split3two(float a, float b, uint& h, uint& m, uint& l) {
    const ushort ah = f2bf(a);
    const float ra = a - bf2f(ah);
    const ushort am_ = f2bf(ra);
    const float ra2 = ra - bf2f(am_);
    const ushort al_ = f2bf(ra2);
    const ushort bh = f2bf(b);
    const float rb = b - bf2f(bh);
    const ushort bm_ = f2bf(rb);
    const float rb2 = rb - bf2f(bm_);
    const ushort bl_ = f2bf(rb2);
    h = (uint)ah | ((uint)bh << 16);
    m = (uint)am_ | ((uint)bm_ << 16);
    l = (uint)al_ | ((uint)bl_ << 16);
}

// ---------------------------------------------------------------------------
// K0 prep: one kernel, 2096 blocks x 256 thr.
//  blocks [0,2048): cos/sin table CS[j][t] = (cos, sin)(t * expf(j*kfac))
//                   -- bit-identical trig expressions to the validated rounds.
//  blocks [2048,2080): q[b][h] = x[b,0,:] @ W0 (RoPE at pos 0 = identity);
//                      hc==0 blocks also zero y.
//  blocks [2080,2096): W1 (fp32 [k][c]) -> 3 RNE bf16 planes, MFMA-fragment-
//                      linear layout (same as validated R5).
// ---------------------------------------------------------------------------
__global__ __launch_bounds__(256) void prep_kernel(const float* __restrict__ x,
                                                   const float* __restrict__ W0,
                                                   const float* __restrict__ W1,
                                                   float* __restrict__ q,
                                                   float* __restrict__ y,
                                                   ushort* __restrict__ wt,
                                                   float* __restrict__ cs) {
    __shared__ float sh[64 * 65];
    const int bid = blockIdx.x;
    const int tid = threadIdx.x;

    if (bid < 2048) {
        // ---- cs table: 64 t x 4 j per block ----
        const int t = ((bid & 63) << 6) | (tid & 63);
        const int j = ((bid >> 6) << 2) | (tid >> 6);
        const float kfac = (float)(-9.210340371976184 / 128.0);  // -ln(1e4)/128
        const float d = expf((float)j * kfac);
        float sv, cv;
        sincosf((float)t * d, &sv, &cv);
        *(float2*)(cs + ((size_t)j * SS + t) * 2) = make_float2(cv, sv);
    } else if (bid < 2080) {
        // ---- q part ----
        const int qb = bid - 2048;
        const int b = qb >> 3;
        const int hc = qb & 7;
        if (hc == 0) y[b * DD + tid] = 0.f;
        const int hk = tid & 31;
        const int iseg = tid >> 5;
        const int h = hc * 32 + hk;
        const float* xrow = x + (size_t)b * SS * DD;
        float p = 0.f;
#pragma unroll
        for (int k = 0; k < 32; ++k) {
            const int i = iseg * 32 + k;
            p = fmaf(xrow[i], W0[i * DD + h], p);
        }
        sh[tid] = p;
        __syncthreads();
        if (tid < 32) {
            float s = 0.f;
#pragma unroll
            for (int jj = 0; jj < 8; ++jj) s += sh[jj * 32 + tid];
            q[b * DD + hc * 32 + tid] = s;
        }
    } else {
        // ---- W1 convert: 64x64 tile ----
        const int cb = bid - 2080;
        const int k0 = (cb & 3) * 64;
        const int c0 = (cb >> 2) * 64;
        {
            const int kr = tid >> 2;
            const int csg = tid & 3;
            const float* src = W1 + (size_t)(k0 + kr) * DD + c0 + csg * 16;
#pragma unroll
            for (int i = 0; i < 4; ++i) {
                const float4 v = *(const float4*)(src + i * 4);
                sh[kr * 65 + csg * 16 + i * 4 + 0] = v.x;
                sh[kr * 65 + csg * 16 + i * 4 + 1] = v.y;
                sh[kr * 65 + csg * 16 + i * 4 + 2] = v.z;
                sh[kr * 65 + csg * 16 + i * 4 + 3] = v.w;
            }
        }
        __syncthreads();
        {
            const int cr = tid >> 2;
            const int ks2 = tid & 3;
            const int c = c0 + cr;
#pragma unroll
            for (int oct = 0; oct < 2; ++oct) {
                const int k = k0 + ks2 * 16 + oct * 8;
                const int kl = ks2 * 16 + oct * 8;
                uint H[4], M[4], L[4];
#pragma unroll
                for (int i = 0; i < 4; ++i) {
                    const float fa = sh[(kl + 2 * i + 0) * 65 + cr];
                    const float fb = sh[(kl + 2 * i + 1) * 65 + cr];
                    split3two(fa, fb, H[i], M[i], L[i]);
                }
                const size_t idx = ((size_t)(c >> 4) * 8 + (k >> 5)) * 512
                                 + (size_t)((k >> 3) & 3) * 128 + (size_t)(c & 15) * 8;
                *(uint4*)(wt + idx) = make_uint4(H[0], H[1], H[2], H[3]);
                *(uint4*)(wt + WT_PLANE + idx) = make_uint4(M[0], M[1], M[2], M[3]);
                *(uint4*)(wt + 2 * WT_PLANE + idx) = make_uint4(L[0], L[1], L[2], L[3]);
            }
        }
    }
}

// ---------------------------------------------------------------------------
// K1: scores[b][t] = q_b . R_t( x[b,t,:] @ W1 )   (3-way-split 6-pass MFMA)
// grid 512 (4 b x 128 blocks of 32 rows), 512 thr = 8 waves (4 ch x 2 kh).
// Stage (once): x tile -> 3 bf16 planes in LDS, XOR-swizzled 16B slots.
// Wave: 32 rows x 64 cols x 128 k: acc[2rt][4ct], 48 MFMA + 12 B-loads/chunk.
// W read exactly once per block (ch x kh disjoint). kh=1 dumps raw acc to
// LDS; kh=0 combines, then epilogue: u from precomputed cs table + q, dot,
// 16-lane butterfly, 4-way ch combine.
// ---------------------------------------------------------------------------
__global__ __launch_bounds__(512, 3) void scores_mfma(const float* __restrict__ x,
                                                      const ushort* __restrict__ wt,
                                                      const float* __restrict__ q,
                                                      const float* __restrict__ cs,
                                                      float* __restrict__ scores) {
    __shared__ __align__(16) unsigned char smem[49152];  // 3 planes x 32 rows x 512 B
    __shared__ float scomb[4][32];
    __shared__ float q_s[256];
    const int tid = threadIdx.x;
    const int bid = blockIdx.x;
    const int b = bid >> 7;
    const int row0 = (bid & 127) << 5;

    if (tid < 256) q_s[tid] = q[b * DD + tid];

    // ---- stage: 512 thr x 16 floats -> 3 bf16 planes, swizzled ----
    {
        const int r = tid >> 4;             // 32 rows
        const int ks16 = (tid & 15) << 4;   // 16-float k segment
        const float* xr = x + ((size_t)(b * SS + row0 + r)) * DD + ks16;
        const int swz = (r & 15) << 4;
        uint H[8], M[8], L[8];
#pragma unroll
        for (int i = 0; i < 4; ++i) {
            const float4 f = *(const float4*)(xr + i * 4);
            split3two(f.x, f.y, H[2 * i], M[2 * i], L[2 * i]);
            split3two(f.z, f.w, H[2 * i + 1], M[2 * i + 1], L[2 * i + 1]);
        }
        const int s0 = (tid & 15) << 1;     // 16B slot index (2 per thread)
        const int off0 = r * 512 + (((s0 + 0) << 4) ^ swz);
        const int off1 = r * 512 + (((s0 + 1) << 4) ^ swz);
        *(uint4*)(smem + off0) = make_uint4(H[0], H[1], H[2], H[3]);
        *(uint4*)(smem + off1) = make_uint4(H[4], H[5], H[6], H[7]);
        *(uint4*)(smem + 16384 + off0) = make_uint4(M[0], M[1], M[2], M[3]);
        *(uint4*)(smem + 16384 + off1) = make_uint4(M[4], M[5], M[6], M[7]);
        *(uint4*)(smem + 32768 + off0) = make_uint4(L[0], L[1], L[2], L[3]);
        *(uint4*)(smem + 32768 + off1) = make_uint4(L[4], L[5], L[6], L[7]);
    }
    __syncthreads();

    const int lane = tid & 63;
    const int wv = tid >> 6;   // 0..7
    const int ch = wv & 3;     // 64-col group
    const int kh = wv >> 2;    // k half
    const int l15 = lane & 15;
    const int hg = lane >> 4;  // 0..3

    f4v acc[2][4];
#pragma unroll
    for (int rt = 0; rt < 2; ++rt)
#pragma unroll
        for (int ct = 0; ct < 4; ++ct) acc[rt][ct] = {0.f, 0.f, 0.f, 0.f};

    const ushort* wb = wt + (size_t)lane * 8;  // lane-linear fragment base
    const int aswz = l15 << 4;

#pragma unroll
    for (int ci = 0; ci < 4; ++ci) {
        const int ks = kh * 4 + ci;
        bf8v a_h[2], a_m[2], a_l[2];
#pragma unroll
        for (int rt = 0; rt < 2; ++rt) {
            const int off = (rt * 16 + l15) * 512 + ((((ks * 4 + hg) << 4)) ^ aswz);
            a_h[rt] = *(const bf8v*)(smem + off);
            a_m[rt] = *(const bf8v*)(smem + 16384 + off);
            a_l[rt] = *(const bf8v*)(smem + 32768 + off);
        }
#pragma unroll
        for (int ct = 0; ct < 4; ++ct) {
            const int gct = ch * 4 + ct;
            const ushort* bp = wb + (size_t)(gct * 8 + ks) * 512;
            const bf8v b_h = *(const bf8v*)(bp);
            const bf8v b_m = *(const bf8v*)(bp + WT_PLANE);
            const bf8v b_l = *(const bf8v*)(bp + 2 * WT_PLANE);
#pragma unroll
            for (int rt = 0; rt < 2; ++rt) {
                acc[rt][ct] = __builtin_amdgcn_mfma_f32_16x16x32_bf16(a_h[rt], b_h, acc[rt][ct], 0, 0, 0);
                acc[rt][ct] = __builtin_amdgcn_mfma_f32_16x16x32_bf16(a_h[rt], b_m, acc[rt][ct], 0, 0, 0);
                acc[rt][ct] = __builtin_amdgcn_mfma_f32_16x16x32_bf16(a_m[rt], b_h, acc[rt][ct], 0, 0, 0);
                acc[rt][ct] = __builtin_amdgcn_mfma_f32_16x16x32_bf16(a_h[rt], b_l, acc[rt][ct], 0, 0, 0);
                acc[rt][ct] = __builtin_amdgcn_mfma_f32_16x16x32_bf16(a_m[rt], b_m, acc[rt][ct], 0, 0, 0);
                acc[rt][ct] = __builtin_amdgcn_mfma_f32_16x16x32_bf16(a_l[rt], b_h, acc[rt][ct], 0, 0, 0);
            }
        }
    }

    // ---- k-half combine via LDS (reuse stage memory) ----
    __syncthreads();
    if (kh == 1) {
#pragma unroll
        for (int rt = 0; rt < 2; ++rt)
#pragma unroll
            for (int ct = 0; ct < 4; ++ct)
                *(f4v*)(smem + (size_t)(((ch * 8 + rt * 4 + ct) * 64 + lane) * 16)) = acc[rt][ct];
    }
    __syncthreads();
    if (kh == 0) {
#pragma unroll
        for (int rt = 0; rt < 2; ++rt)
#pragma unroll
            for (int ct = 0; ct < 4; ++ct)
                acc[rt][ct] += *(const f4v*)(smem + (size_t)(((ch * 8 + rt * 4 + ct) * 64 + lane) * 16));

        // ---- epilogue: u from cs table + q; dot; reduce ----
        const int par = l15 & 1;
        float p[2][4];
#pragma unroll
        for (int rt = 0; rt < 2; ++rt)
#pragma unroll
            for (int i = 0; i < 4; ++i) p[rt][i] = 0.f;

#pragma unroll
        for (int ct = 0; ct < 4; ++ct) {
            const int c = ch * 64 + ct * 16 + l15;
            const int j = c >> 1;
            const float qe = q_s[2 * j], qo = q_s[2 * j + 1];
            const float* csp = cs + (size_t)j * (SS * 2);
#pragma unroll
            for (int rt = 0; rt < 2; ++rt) {
                const int t0 = row0 + rt * 16 + hg * 4;
                const float4 csA = *(const float4*)(csp + t0 * 2);
                const float4 csB = *(const float4*)(csp + t0 * 2 + 4);
                const float u0 = par ? (qo * csA.x - qe * csA.y) : (qe * csA.x + qo * csA.y);
                const float u1 = par ? (qo * csA.z - qe * csA.w) : (qe * csA.z + qo * csA.w);
                const float u2 = par ? (qo * csB.x - qe * csB.y) : (qe * csB.x + qo * csB.y);
                const float u3 = par ? (qo * csB.z - qe * csB.w) : (qe * csB.z + qo * csB.w);
                p[rt][0] = fmaf(acc[rt][ct][0], u0, p[rt][0]);
                p[rt][1] = fmaf(acc[rt][ct][1], u1, p[rt][1]);
                p[rt][2] = fmaf(acc[rt][ct][2], u2, p[rt][2]);
                p[rt][3] = fmaf(acc[rt][ct][3], u3, p[rt][3]);
            }
        }
#pragma unroll
        for (int rt = 0; rt < 2; ++rt) {
#pragma unroll
            for (int off = 1; off <= 8; off <<= 1) {
                p[rt][0] += __shfl_xor(p[rt][0], off);
                p[rt][1] += __shfl_xor(p[rt][1], off);
                p[rt][2] += __shfl_xor(p[rt][2], off);
                p[rt][3] += __shfl_xor(p[rt][3], off);
            }
            if (l15 == 0)
                *(float4*)&scomb[ch][rt * 16 + hg * 4] =
                    make_float4(p[rt][0], p[rt][1], p[rt][2], p[rt][3]);
        }
    }
    __syncthreads();
    if (tid < 32)
        scores[(size_t)b * SS + row0 + tid] =
            ((scomb[0][tid] + scomb[1][tid]) + scomb[2][tid]) + scomb[3][tid];
}

// ---------------------------------------------------------------------------
// K2: fused softmax + weighted row-sum (attn ~one-hot: skip exact zeros).
// ---------------------------------------------------------------------------
__global__ __launch_bounds__(256) void fused_kernel(const float* __restrict__ x,
                                                    const float* __restrict__ scores,
                                                    float* __restrict__ y) {
    const int c = blockIdx.x;
    const int b = blockIdx.y;
    const int tid = threadIdx.x;
    const int lane = tid & 63;
    const int wid = tid >> 6;
    const float* sb = scores + (size_t)b * SS;

    float4 v[4];
    float m = -INFINITY;
#pragma unroll
    for (int i = 0; i < 4; ++i) {
        v[i] = *(const float4*)(sb + tid * 16 + i * 4);
        m = fmaxf(m, fmaxf(fmaxf(v[i].x, v[i].y), fmaxf(v[i].z, v[i].w)));
    }
#pragma unroll
    for (int off = 32; off >= 1; off >>= 1) m = fmaxf(m, __shfl_xor(m, off));
    __shared__ float redm[4];
    __shared__ float reds[4];
    __shared__ float a_s[64];
    if (lane == 0) redm[wid] = m;
    __syncthreads();
    const float M = fmaxf(fmaxf(redm[0], redm[1]), fmaxf(redm[2], redm[3]));

    float s = 0.f;
#pragma unroll
    for (int i = 0; i < 4; ++i) {
        s += expf(v[i].x - M);
        s += expf(v[i].y - M);
        s += expf(v[i].z - M);
        s += expf(v[i].w - M);
    }
#pragma unroll
    for (int off = 32; off >= 1; off >>= 1) s += __shfl_xor(s, off);
    if (lane == 0) reds[wid] = s;
    __syncthreads();
    const float S = ((reds[0] + reds[1]) + reds[2]) + reds[3];
    const float inv = 1.0f / S;

    if (tid < 64) a_s[tid] = expf(sb[c * 64 + tid] - M) * inv;
    __syncthreads();

    float accv = 0.f;
    for (int t = 0; t < 64; ++t) {
        const float a = a_s[t];
        if (a != 0.f)
            accv = fmaf(a, x[((size_t)(b * SS + c * 64 + t)) * DD + tid], accv);
    }
    atomicAdd(&y[b * DD + tid], accv);
}

// ---------------------------------------------------------------------------
// K3: out[b][o] = sum_i y[b][i] * W2[i][o]. grid 4, block 256, direct write.
// ---------------------------------------------------------------------------
__global__ __launch_bounds__(256) void out_kernel(const float* __restrict__ y,
                                                  const float* __restrict__ W2,
                                                  float* __restrict__ out) {
    const int b = blockIdx.x;
    const int o = threadIdx.x;
    __shared__ float y_s[DD];
    y_s[o] = y[b * DD + o];
    __syncthreads();
    float p = 0.f;
#pragma unroll 8
    for (int i = 0; i < DD; ++i) p = fmaf(y_s[i], W2[(size_t)i * DD + o], p);
    out[b * DD + o] = p;
}

// ---------------------------------------------------------------------------
extern "C" void kernel_launch(void* const* d_in, const int* in_sizes, int n_in,
                              void* d_out, int out_size, void* d_ws, size_t ws_size,
                              hipStream_t stream) {
    const float* x = (const float*)d_in[0];
    const float* W0 = (const float*)d_in[1];
    const float* W1 = (const float*)d_in[2];
    const float* W2 = (const float*)d_in[3];
    float* ws = (float*)d_ws;
    float* q = ws;                       // 1024 floats
    float* scores = ws + 1024;           // 16384 floats
    float* y = ws + 17408;               // 1024 floats
    ushort* wt = (ushort*)(ws + 18432);  // 3 planes x 65536 shorts = 384 KB
    float* cs = ws + 116736;             // 128*4096*2 floats = 4 MB
    float* out = (float*)d_out;

    prep_kernel<<<dim3(2096), 256, 0, stream>>>(x, W0, W1, q, y, wt, cs);
    scores_mfma<<<dim3(512), 512, 0, stream>>>(x, wt, q, cs, scores);
    fused_kernel<<<dim3(64, BB), 256, 0, stream>>>(x, scores, y);
    out_kernel<<<dim3(BB), 256, 0, stream>>>(y, W2, out);
}

// Round 7
// 36.608 us; speedup vs baseline: 2.1590x; 1.0212x over previous
//
#include <hip/hip_runtime.h>
#include <math.h>

#define BB 4
#define SS 4096
#define DD 256
#define WT_PLANE 65536  // shorts per W1 bf16 plane (256x256)

typedef __attribute__((ext_vector_type(8))) short bf8v;  // 8 bf16 (4 VGPRs)
typedef __attribute__((ext_vector_type(4))) float f4v;   // MFMA accumulator

// ---- bf16 helpers (RNE) ----
__device__ __forceinline__ ushort f2bf(float f) {
    uint u = __float_as_uint(f);
    u += 0x7fffu + ((u >> 16) & 1u);
    return (ushort)(u >> 16);
}
__device__ __forceinline__ float bf2f(ushort h) {
    return __uint_as_float(((uint)h) << 16);
}
// 3-way split of two floats, packed per plane: a = h + m + l (+ ~2^-27 rel)
__device__ __forceinline__ void split3two(float a, float b, uint& h, uint& m, uint& l) {
    const ushort ah = f2bf(a);
    const float ra = a - bf2f(ah);
    const ushort am_ = f2bf(ra);
    const float ra2 = ra - bf2f(am_);
    const ushort al_ = f2bf(ra2);
    const ushort bh = f2bf(b);
    const float rb = b - bf2f(bh);
    const ushort bm_ = f2bf(rb);
    const float rb2 = rb - bf2f(bm_);
    const ushort bl_ = f2bf(rb2);
    h = (uint)ah | ((uint)bh << 16);
    m = (uint)am_ | ((uint)bm_ << 16);
    l = (uint)al_ | ((uint)bl_ << 16);
}

// ---------------------------------------------------------------------------
// K0 prep: one kernel, 2096 blocks x 256 thr.
//  blocks [0,2048): cos/sin table CS[j][t] = (cos, sin)(t * expf(j*kfac))
//  blocks [2048,2080): q[b][h] = x[b,0,:] @ W0 (RoPE at pos 0 = identity);
//                      hc==0 blocks also zero y.
//  blocks [2080,2096): W1 (fp32 [k][c]) -> 3 RNE bf16 planes, MFMA-fragment-
//                      linear layout.
// ---------------------------------------------------------------------------
__global__ __launch_bounds__(256) void prep_kernel(const float* __restrict__ x,
                                                   const float* __restrict__ W0,
                                                   const float* __restrict__ W1,
                                                   float* __restrict__ q,
                                                   float* __restrict__ y,
                                                   ushort* __restrict__ wt,
                                                   float* __restrict__ cs) {
    __shared__ float sh[64 * 65];
    const int bid = blockIdx.x;
    const int tid = threadIdx.x;

    if (bid < 2048) {
        const int t = ((bid & 63) << 6) | (tid & 63);
        const int j = ((bid >> 6) << 2) | (tid >> 6);
        const float kfac = (float)(-9.210340371976184 / 128.0);  // -ln(1e4)/128
        const float d = expf((float)j * kfac);
        float sv, cv;
        sincosf((float)t * d, &sv, &cv);
        *(float2*)(cs + ((size_t)j * SS + t) * 2) = make_float2(cv, sv);
    } else if (bid < 2080) {
        const int qb = bid - 2048;
        const int b = qb >> 3;
        const int hc = qb & 7;
        if (hc == 0) y[b * DD + tid] = 0.f;
        const int hk = tid & 31;
        const int iseg = tid >> 5;
        const int h = hc * 32 + hk;
        const float* xrow = x + (size_t)b * SS * DD;
        float p = 0.f;
#pragma unroll
        for (int k = 0; k < 32; ++k) {
            const int i = iseg * 32 + k;
            p = fmaf(xrow[i], W0[i * DD + h], p);
        }
        sh[tid] = p;
        __syncthreads();
        if (tid < 32) {
            float s = 0.f;
#pragma unroll
            for (int jj = 0; jj < 8; ++jj) s += sh[jj * 32 + tid];
            q[b * DD + hc * 32 + tid] = s;
        }
    } else {
        const int cb = bid - 2080;
        const int k0 = (cb & 3) * 64;
        const int c0 = (cb >> 2) * 64;
        {
            const int kr = tid >> 2;
            const int csg = tid & 3;
            const float* src = W1 + (size_t)(k0 + kr) * DD + c0 + csg * 16;
#pragma unroll
            for (int i = 0; i < 4; ++i) {
                const float4 v = *(const float4*)(src + i * 4);
                sh[kr * 65 + csg * 16 + i * 4 + 0] = v.x;
                sh[kr * 65 + csg * 16 + i * 4 + 1] = v.y;
                sh[kr * 65 + csg * 16 + i * 4 + 2] = v.z;
                sh[kr * 65 + csg * 16 + i * 4 + 3] = v.w;
            }
        }
        __syncthreads();
        {
            const int cr = tid >> 2;
            const int ks2 = tid & 3;
            const int c = c0 + cr;
#pragma unroll
            for (int oct = 0; oct < 2; ++oct) {
                const int k = k0 + ks2 * 16 + oct * 8;
                const int kl = ks2 * 16 + oct * 8;
                uint H[4], M[4], L[4];
#pragma unroll
                for (int i = 0; i < 4; ++i) {
                    const float fa = sh[(kl + 2 * i + 0) * 65 + cr];
                    const float fb = sh[(kl + 2 * i + 1) * 65 + cr];
                    split3two(fa, fb, H[i], M[i], L[i]);
                }
                const size_t idx = ((size_t)(c >> 4) * 8 + (k >> 5)) * 512
                                 + (size_t)((k >> 3) & 3) * 128 + (size_t)(c & 15) * 8;
                *(uint4*)(wt + idx) = make_uint4(H[0], H[1], H[2], H[3]);
                *(uint4*)(wt + WT_PLANE + idx) = make_uint4(M[0], M[1], M[2], M[3]);
                *(uint4*)(wt + 2 * WT_PLANE + idx) = make_uint4(L[0], L[1], L[2], L[3]);
            }
        }
    }
}

// ---------------------------------------------------------------------------
// K1: scores[b][t] = q_b . R_t( x[b,t,:] @ W1 )   (3-way-split 6-pass MFMA)
// grid 512 (4 b x 128 blocks of 32 rows), 512 thr = 8 waves, each wave one
// DISJOINT 32-col group over the full K=256 (no k-split: no acc combine, no
// extra syncs, all waves run the epilogue).
// ks-loop fully unrolled with a 2-deep register double-buffer of B frags
// (next ks's 6 B loads issued before current 24 MFMAs) -> L2 latency hidden.
// W read exactly once per block. Epilogue: u from cs table + q, dot, 16-lane
// butterfly, 8-way LDS combine. Same numerics as validated R6.
// ---------------------------------------------------------------------------
__global__ __launch_bounds__(512, 4) void scores_mfma(const float* __restrict__ x,
                                                      const ushort* __restrict__ wt,
                                                      const float* __restrict__ q,
                                                      const float* __restrict__ cs,
                                                      float* __restrict__ scores) {
    __shared__ __align__(16) unsigned char smem[49152];  // 3 planes x 32 rows x 512 B
    __shared__ float scomb[8][32];
    __shared__ float q_s[256];
    const int tid = threadIdx.x;
    const int bid = blockIdx.x;
    const int b = bid >> 7;
    const int row0 = (bid & 127) << 5;

    if (tid < 256) q_s[tid] = q[b * DD + tid];

    // ---- stage: 512 thr x 16 floats -> 3 bf16 planes, swizzled ----
    {
        const int r = tid >> 4;            // 32 rows
        const int ks16 = (tid & 15) << 4;  // 16-float k segment
        const float* xr = x + ((size_t)(b * SS + row0 + r)) * DD + ks16;
        const int swz = (r & 15) << 4;
        uint H[8], M[8], L[8];
#pragma unroll
        for (int i = 0; i < 4; ++i) {
            const float4 f = *(const float4*)(xr + i * 4);
            split3two(f.x, f.y, H[2 * i], M[2 * i], L[2 * i]);
            split3two(f.z, f.w, H[2 * i + 1], M[2 * i + 1], L[2 * i + 1]);
        }
        const int s0 = (tid & 15) << 1;
        const int off0 = r * 512 + (((s0 + 0) << 4) ^ swz);
        const int off1 = r * 512 + (((s0 + 1) << 4) ^ swz);
        *(uint4*)(smem + off0) = make_uint4(H[0], H[1], H[2], H[3]);
        *(uint4*)(smem + off1) = make_uint4(H[4], H[5], H[6], H[7]);
        *(uint4*)(smem + 16384 + off0) = make_uint4(M[0], M[1], M[2], M[3]);
        *(uint4*)(smem + 16384 + off1) = make_uint4(M[4], M[5], M[6], M[7]);
        *(uint4*)(smem + 32768 + off0) = make_uint4(L[0], L[1], L[2], L[3]);
        *(uint4*)(smem + 32768 + off1) = make_uint4(L[4], L[5], L[6], L[7]);
    }
    __syncthreads();

    const int lane = tid & 63;
    const int ch = tid >> 6;   // 0..7: 32-col group
    const int l15 = lane & 15;
    const int hg = lane >> 4;  // 0..3

    f4v acc[2][2];  // [rt][ct]
#pragma unroll
    for (int rt = 0; rt < 2; ++rt)
#pragma unroll
        for (int ct = 0; ct < 2; ++ct) acc[rt][ct] = {0.f, 0.f, 0.f, 0.f};

    const ushort* wb = wt + (size_t)lane * 8;  // lane-linear fragment base
    const int aswz = l15 << 4;

    // B-fragment register double-buffer (compile-time buffer indices)
    bf8v Bh[2][2], Bm[2][2], Bl[2][2];  // [buf][ct]
#pragma unroll
    for (int ct = 0; ct < 2; ++ct) {
        const ushort* bp = wb + (size_t)(((ch * 2 + ct) * 8 + 0) * 512);
        Bh[0][ct] = *(const bf8v*)(bp);
        Bm[0][ct] = *(const bf8v*)(bp + WT_PLANE);
        Bl[0][ct] = *(const bf8v*)(bp + 2 * WT_PLANE);
    }

#pragma unroll
    for (int ks = 0; ks < 8; ++ks) {
        const int cur = ks & 1;
        const int nxt = cur ^ 1;
        if (ks < 7) {
#pragma unroll
            for (int ct = 0; ct < 2; ++ct) {
                const ushort* bp = wb + (size_t)(((ch * 2 + ct) * 8 + ks + 1) * 512);
                Bh[nxt][ct] = *(const bf8v*)(bp);
                Bm[nxt][ct] = *(const bf8v*)(bp + WT_PLANE);
                Bl[nxt][ct] = *(const bf8v*)(bp + 2 * WT_PLANE);
            }
        }
        bf8v a_h[2], a_m[2], a_l[2];
#pragma unroll
        for (int rt = 0; rt < 2; ++rt) {
            const int off = (rt * 16 + l15) * 512 + ((((ks * 4 + hg) << 4)) ^ aswz);
            a_h[rt] = *(const bf8v*)(smem + off);
            a_m[rt] = *(const bf8v*)(smem + 16384 + off);
            a_l[rt] = *(const bf8v*)(smem + 32768 + off);
        }
#pragma unroll
        for (int ct = 0; ct < 2; ++ct) {
#pragma unroll
            for (int rt = 0; rt < 2; ++rt) {
                acc[rt][ct] = __builtin_amdgcn_mfma_f32_16x16x32_bf16(a_h[rt], Bh[cur][ct], acc[rt][ct], 0, 0, 0);
                acc[rt][ct] = __builtin_amdgcn_mfma_f32_16x16x32_bf16(a_h[rt], Bm[cur][ct], acc[rt][ct], 0, 0, 0);
                acc[rt][ct] = __builtin_amdgcn_mfma_f32_16x16x32_bf16(a_m[rt], Bh[cur][ct], acc[rt][ct], 0, 0, 0);
                acc[rt][ct] = __builtin_amdgcn_mfma_f32_16x16x32_bf16(a_h[rt], Bl[cur][ct], acc[rt][ct], 0, 0, 0);
                acc[rt][ct] = __builtin_amdgcn_mfma_f32_16x16x32_bf16(a_m[rt], Bm[cur][ct], acc[rt][ct], 0, 0, 0);
                acc[rt][ct] = __builtin_amdgcn_mfma_f32_16x16x32_bf16(a_l[rt], Bh[cur][ct], acc[rt][ct], 0, 0, 0);
            }
        }
    }

    // ---- epilogue: u from cs table + q; dot; 16-lane reduce; LDS combine ----
    const int par = l15 & 1;
    float p[2][4];
#pragma unroll
    for (int rt = 0; rt < 2; ++rt)
#pragma unroll
        for (int i = 0; i < 4; ++i) p[rt][i] = 0.f;

#pragma unroll
    for (int ct = 0; ct < 2; ++ct) {
        const int c = (ch * 2 + ct) * 16 + l15;
        const int j = c >> 1;
        const float qe = q_s[2 * j], qo = q_s[2 * j + 1];
        const float* csp = cs + (size_t)j * (SS * 2);
#pragma unroll
        for (int rt = 0; rt < 2; ++rt) {
            const int t0 = row0 + rt * 16 + hg * 4;
            const float4 csA = *(const float4*)(csp + t0 * 2);
            const float4 csB = *(const float4*)(csp + t0 * 2 + 4);
            const float u0 = par ? (qo * csA.x - qe * csA.y) : (qe * csA.x + qo * csA.y);
            const float u1 = par ? (qo * csA.z - qe * csA.w) : (qe * csA.z + qo * csA.w);
            const float u2 = par ? (qo * csB.x - qe * csB.y) : (qe * csB.x + qo * csB.y);
            const float u3 = par ? (qo * csB.z - qe * csB.w) : (qe * csB.z + qo * csB.w);
            p[rt][0] = fmaf(acc[rt][ct][0], u0, p[rt][0]);
            p[rt][1] = fmaf(acc[rt][ct][1], u1, p[rt][1]);
            p[rt][2] = fmaf(acc[rt][ct][2], u2, p[rt][2]);
            p[rt][3] = fmaf(acc[rt][ct][3], u3, p[rt][3]);
        }
    }
#pragma unroll
    for (int rt = 0; rt < 2; ++rt) {
#pragma unroll
        for (int off = 1; off <= 8; off <<= 1) {
            p[rt][0] += __shfl_xor(p[rt][0], off);
            p[rt][1] += __shfl_xor(p[rt][1], off);
            p[rt][2] += __shfl_xor(p[rt][2], off);
            p[rt][3] += __shfl_xor(p[rt][3], off);
        }
        if (l15 == 0)
            *(float4*)&scomb[ch][rt * 16 + hg * 4] =
                make_float4(p[rt][0], p[rt][1], p[rt][2], p[rt][3]);
    }
    __syncthreads();
    if (tid < 32) {
        float s = 0.f;
#pragma unroll
        for (int g = 0; g < 8; ++g) s += scomb[g][tid];
        scores[(size_t)b * SS + row0 + tid] = s;
    }
}

// ---------------------------------------------------------------------------
// K2: fused softmax + weighted row-sum (attn ~one-hot: skip exact zeros).
// ---------------------------------------------------------------------------
__global__ __launch_bounds__(256) void fused_kernel(const float* __restrict__ x,
                                                    const float* __restrict__ scores,
                                                    float* __restrict__ y) {
    const int c = blockIdx.x;
    const int b = blockIdx.y;
    const int tid = threadIdx.x;
    const int lane = tid & 63;
    const int wid = tid >> 6;
    const float* sb = scores + (size_t)b * SS;

    float4 v[4];
    float m = -INFINITY;
#pragma unroll
    for (int i = 0; i < 4; ++i) {
        v[i] = *(const float4*)(sb + tid * 16 + i * 4);
        m = fmaxf(m, fmaxf(fmaxf(v[i].x, v[i].y), fmaxf(v[i].z, v[i].w)));
    }
#pragma unroll
    for (int off = 32; off >= 1; off >>= 1) m = fmaxf(m, __shfl_xor(m, off));
    __shared__ float redm[4];
    __shared__ float reds[4];
    __shared__ float a_s[64];
    if (lane == 0) redm[wid] = m;
    __syncthreads();
    const float M = fmaxf(fmaxf(redm[0], redm[1]), fmaxf(redm[2], redm[3]));

    float s = 0.f;
#pragma unroll
    for (int i = 0; i < 4; ++i) {
        s += expf(v[i].x - M);
        s += expf(v[i].y - M);
        s += expf(v[i].z - M);
        s += expf(v[i].w - M);
    }
#pragma unroll
    for (int off = 32; off >= 1; off >>= 1) s += __shfl_xor(s, off);
    if (lane == 0) reds[wid] = s;
    __syncthreads();
    const float S = ((reds[0] + reds[1]) + reds[2]) + reds[3];
    const float inv = 1.0f / S;

    if (tid < 64) a_s[tid] = expf(sb[c * 64 + tid] - M) * inv;
    __syncthreads();

    float accv = 0.f;
    for (int t = 0; t < 64; ++t) {
        const float a = a_s[t];
        if (a != 0.f)
            accv = fmaf(a, x[((size_t)(b * SS + c * 64 + t)) * DD + tid], accv);
    }
    atomicAdd(&y[b * DD + tid], accv);
}

// ---------------------------------------------------------------------------
// K3: out[b][o] = sum_i y[b][i] * W2[i][o]. grid 4, block 256, direct write.
// ---------------------------------------------------------------------------
__global__ __launch_bounds__(256) void out_kernel(const float* __restrict__ y,
                                                  const float* __restrict__ W2,
                                                  float* __restrict__ out) {
    const int b = blockIdx.x;
    const int o = threadIdx.x;
    __shared__ float y_s[DD];
    y_s[o] = y[b * DD + o];
    __syncthreads();
    float p = 0.f;
#pragma unroll 8
    for (int i = 0; i < DD; ++i) p = fmaf(y_s[i], W2[(size_t)i * DD + o], p);
    out[b * DD + o] = p;
}

// ---------------------------------------------------------------------------
extern "C" void kernel_launch(void* const* d_in, const int* in_sizes, int n_in,
                              void* d_out, int out_size, void* d_ws, size_t ws_size,
                              hipStream_t stream) {
    const float* x = (const float*)d_in[0];
    const float* W0 = (const float*)d_in[1];
    const float* W1 = (const float*)d_in[2];
    const float* W2 = (const float*)d_in[3];
    float* ws = (float*)d_ws;
    float* q = ws;                       // 1024 floats
    float* scores = ws + 1024;           // 16384 floats
    float* y = ws + 17408;               // 1024 floats
    ushort* wt = (ushort*)(ws + 18432);  // 3 planes x 65536 shorts = 384 KB
    float* cs = ws + 116736;             // 128*4096*2 floats = 4 MB
    float* out = (float*)d_out;

    prep_kernel<<<dim3(2096), 256, 0, stream>>>(x, W0, W1, q, y, wt, cs);
    scores_mfma<<<dim3(512), 512, 0, stream>>>(x, wt, q, cs, scores);
    fused_kernel<<<dim3(64, BB), 256, 0, stream>>>(x, scores, y);
    out_kernel<<<dim3(BB), 256, 0, stream>>>(y, W2, out);
}

// Round 8
// 33.351 us; speedup vs baseline: 2.3698x; 1.0977x over previous
//
#include <hip/hip_runtime.h>
#include <math.h>

#define BB 4
#define SS 4096
#define DD 256
#define WT_PLANE 65536  // halves per W1 fp16 plane (256x256)

typedef __attribute__((ext_vector_type(8))) _Float16 h8v;  // 8 fp16 (4 VGPRs)
typedef __attribute__((ext_vector_type(4))) float f4v;     // MFMA accumulator

// ---- fp16 split helpers (RNE; splitting lemma: a - (float)ah is exact) ----
__device__ __forceinline__ ushort f2h(float f) {
    _Float16 h = (_Float16)f;
    return __builtin_bit_cast(ushort, h);
}
__device__ __forceinline__ float h2f(ushort u) {
    return (float)__builtin_bit_cast(_Float16, u);
}
// 2-way fp16 split of two floats, packed: a = h + l + O(2^-23)
__device__ __forceinline__ void split2htwo(float a, float b, uint& h, uint& l) {
    const ushort ah = f2h(a);
    const ushort al = f2h(a - h2f(ah));
    const ushort bh = f2h(b);
    const ushort bl = f2h(b - h2f(bh));
    h = (uint)ah | ((uint)bh << 16);
    l = (uint)al | ((uint)bl << 16);
}

// ---------------------------------------------------------------------------
// K0 prep: one kernel, 2096 blocks x 256 thr.
//  blocks [0,2048): cos/sin table CS[j][t] = (cos,sin)(t * expf(j*kfac))
//                   -- bit-identical trig expressions to validated rounds.
//  blocks [2048,2080): q[b][h] = x[b,0,:] @ W0 (RoPE at pos 0 = identity);
//                      hc==0 zeroes y, hc==1 zeroes out (for atomics).
//  blocks [2080,2096): W1 (fp32 [k][c]) -> 2 RNE fp16 planes, MFMA-fragment-
//                      linear layout: idx = ((c>>4)*8+(k>>5))*512
//                                         + ((k>>3)&3)*128 + (c&15)*8 + (k&7)
// ---------------------------------------------------------------------------
__global__ __launch_bounds__(256) void prep_kernel(const float* __restrict__ x,
                                                   const float* __restrict__ W0,
                                                   const float* __restrict__ W1,
                                                   float* __restrict__ q,
                                                   float* __restrict__ y,
                                                   float* __restrict__ out,
                                                   ushort* __restrict__ wt,
                                                   float* __restrict__ cs) {
    __shared__ float sh[64 * 65];
    const int bid = blockIdx.x;
    const int tid = threadIdx.x;

    if (bid < 2048) {
        const int t = ((bid & 63) << 6) | (tid & 63);
        const int j = ((bid >> 6) << 2) | (tid >> 6);
        const float kfac = (float)(-9.210340371976184 / 128.0);  // -ln(1e4)/128
        const float d = expf((float)j * kfac);
        float sv, cv;
        sincosf((float)t * d, &sv, &cv);
        *(float2*)(cs + ((size_t)j * SS + t) * 2) = make_float2(cv, sv);
    } else if (bid < 2080) {
        const int qb = bid - 2048;
        const int b = qb >> 3;
        const int hc = qb & 7;
        if (hc == 0) y[b * DD + tid] = 0.f;
        if (hc == 1) out[b * DD + tid] = 0.f;
        const int hk = tid & 31;
        const int iseg = tid >> 5;
        const int h = hc * 32 + hk;
        const float* xrow = x + (size_t)b * SS * DD;
        float p = 0.f;
#pragma unroll
        for (int k = 0; k < 32; ++k) {
            const int i = iseg * 32 + k;
            p = fmaf(xrow[i], W0[i * DD + h], p);
        }
        sh[tid] = p;
        __syncthreads();
        if (tid < 32) {
            float s = 0.f;
#pragma unroll
            for (int jj = 0; jj < 8; ++jj) s += sh[jj * 32 + tid];
            q[b * DD + hc * 32 + tid] = s;
        }
    } else {
        const int cb = bid - 2080;
        const int k0 = (cb & 3) * 64;
        const int c0 = (cb >> 2) * 64;
        {
            const int kr = tid >> 2;
            const int csg = tid & 3;
            const float* src = W1 + (size_t)(k0 + kr) * DD + c0 + csg * 16;
#pragma unroll
            for (int i = 0; i < 4; ++i) {
                const float4 v = *(const float4*)(src + i * 4);
                sh[kr * 65 + csg * 16 + i * 4 + 0] = v.x;
                sh[kr * 65 + csg * 16 + i * 4 + 1] = v.y;
                sh[kr * 65 + csg * 16 + i * 4 + 2] = v.z;
                sh[kr * 65 + csg * 16 + i * 4 + 3] = v.w;
            }
        }
        __syncthreads();
        {
            const int cr = tid >> 2;
            const int ks2 = tid & 3;
            const int c = c0 + cr;
#pragma unroll
            for (int oct = 0; oct < 2; ++oct) {
                const int k = k0 + ks2 * 16 + oct * 8;
                const int kl = ks2 * 16 + oct * 8;
                uint H[4], L[4];
#pragma unroll
                for (int i = 0; i < 4; ++i) {
                    const float fa = sh[(kl + 2 * i + 0) * 65 + cr];
                    const float fb = sh[(kl + 2 * i + 1) * 65 + cr];
                    split2htwo(fa, fb, H[i], L[i]);
                }
                const size_t idx = ((size_t)(c >> 4) * 8 + (k >> 5)) * 512
                                 + (size_t)((k >> 3) & 3) * 128 + (size_t)(c & 15) * 8;
                *(uint4*)(wt + idx) = make_uint4(H[0], H[1], H[2], H[3]);
                *(uint4*)(wt + WT_PLANE + idx) = make_uint4(L[0], L[1], L[2], L[3]);
            }
        }
    }
}

// ---------------------------------------------------------------------------
// K1: scores[b][t] = q_b . R_t( x[b,t,:] @ W1 )  (2-way fp16 split, 3-pass
// MFMA: ah*bh + ah*bl + al*bh; dropped al*bl ~2^-22 rel — below fp32 noise).
// grid 512 (4 b x 128 blocks of 32 rows), 256 thr = 4 waves; each wave one
// disjoint 64-col group over full K=256. A staged once in LDS (2 fp16 planes,
// XOR-swizzled 16B slots); B streamed coalesced from fragment-linear wt.
// Epilogue: u from cs table + q, dot, 16-lane butterfly, 4-way LDS combine.
// ---------------------------------------------------------------------------
__global__ __launch_bounds__(256, 4) void scores_mfma(const float* __restrict__ x,
                                                      const ushort* __restrict__ wt,
                                                      const float* __restrict__ q,
                                                      const float* __restrict__ cs,
                                                      float* __restrict__ scores) {
    __shared__ __align__(16) unsigned char smem[32768];  // 2 planes x 32 rows x 512 B
    __shared__ float scomb[4][32];
    __shared__ float q_s[256];
    const int tid = threadIdx.x;
    const int bid = blockIdx.x;
    const int b = bid >> 7;
    const int row0 = (bid & 127) << 5;

    q_s[tid] = q[b * DD + tid];

    // ---- stage: 256 thr x 32 floats -> 2 fp16 planes, swizzled ----
    {
        const int r = tid >> 3;            // 32 rows, 8 threads each
        const int seg = tid & 7;           // 32-float k segment
        const float* xr = x + ((size_t)(b * SS + row0 + r)) * DD + seg * 32;
        const int swz = (r & 15) << 4;
#pragma unroll
        for (int j = 0; j < 4; ++j) {
            const float4 f0 = *(const float4*)(xr + j * 8);
            const float4 f1 = *(const float4*)(xr + j * 8 + 4);
            uint H[4], L[4];
            split2htwo(f0.x, f0.y, H[0], L[0]);
            split2htwo(f0.z, f0.w, H[1], L[1]);
            split2htwo(f1.x, f1.y, H[2], L[2]);
            split2htwo(f1.z, f1.w, H[3], L[3]);
            const int s = seg * 4 + j;     // 16B slot (8 fp16)
            const int off = r * 512 + (((s << 4)) ^ swz);
            *(uint4*)(smem + off) = make_uint4(H[0], H[1], H[2], H[3]);
            *(uint4*)(smem + 16384 + off) = make_uint4(L[0], L[1], L[2], L[3]);
        }
    }
    __syncthreads();

    const int lane = tid & 63;
    const int wv = tid >> 6;   // 0..3: 64-col group
    const int l15 = lane & 15;
    const int hg = lane >> 4;  // 0..3

    f4v acc[2][4];  // [rt][ct]
#pragma unroll
    for (int rt = 0; rt < 2; ++rt)
#pragma unroll
        for (int ct = 0; ct < 4; ++ct) acc[rt][ct] = {0.f, 0.f, 0.f, 0.f};

    const ushort* wb = wt + (size_t)lane * 8;  // lane-linear fragment base
    const int aswz = l15 << 4;

#pragma unroll
    for (int ks = 0; ks < 8; ++ks) {
        h8v a_h[2], a_l[2];
#pragma unroll
        for (int rt = 0; rt < 2; ++rt) {
            const int off = (rt * 16 + l15) * 512 + ((((ks * 4 + hg) << 4)) ^ aswz);
            a_h[rt] = *(const h8v*)(smem + off);
            a_l[rt] = *(const h8v*)(smem + 16384 + off);
        }
#pragma unroll
        for (int ct = 0; ct < 4; ++ct) {
            const int gct = wv * 4 + ct;
            const ushort* bp = wb + (size_t)(gct * 8 + ks) * 512;
            const h8v b_h = *(const h8v*)(bp);
            const h8v b_l = *(const h8v*)(bp + WT_PLANE);
#pragma unroll
            for (int rt = 0; rt < 2; ++rt) {
                acc[rt][ct] = __builtin_amdgcn_mfma_f32_16x16x32_f16(a_h[rt], b_h, acc[rt][ct], 0, 0, 0);
                acc[rt][ct] = __builtin_amdgcn_mfma_f32_16x16x32_f16(a_h[rt], b_l, acc[rt][ct], 0, 0, 0);
                acc[rt][ct] = __builtin_amdgcn_mfma_f32_16x16x32_f16(a_l[rt], b_h, acc[rt][ct], 0, 0, 0);
            }
        }
    }

    // ---- epilogue: u from cs table + q; dot; 16-lane reduce; LDS combine ----
    const int par = l15 & 1;
    float p[2][4];
#pragma unroll
    for (int rt = 0; rt < 2; ++rt)
#pragma unroll
        for (int i = 0; i < 4; ++i) p[rt][i] = 0.f;

#pragma unroll
    for (int ct = 0; ct < 4; ++ct) {
        const int c = (wv * 4 + ct) * 16 + l15;
        const int j = c >> 1;
        const float qe = q_s[2 * j], qo = q_s[2 * j + 1];
        const float* csp = cs + (size_t)j * (SS * 2);
#pragma unroll
        for (int rt = 0; rt < 2; ++rt) {
            const int t0 = row0 + rt * 16 + hg * 4;
            const float4 csA = *(const float4*)(csp + t0 * 2);
            const float4 csB = *(const float4*)(csp + t0 * 2 + 4);
            const float u0 = par ? (qo * csA.x - qe * csA.y) : (qe * csA.x + qo * csA.y);
            const float u1 = par ? (qo * csA.z - qe * csA.w) : (qe * csA.z + qo * csA.w);
            const float u2 = par ? (qo * csB.x - qe * csB.y) : (qe * csB.x + qo * csB.y);
            const float u3 = par ? (qo * csB.z - qe * csB.w) : (qe * csB.z + qo * csB.w);
            p[rt][0] = fmaf(acc[rt][ct][0], u0, p[rt][0]);
            p[rt][1] = fmaf(acc[rt][ct][1], u1, p[rt][1]);
            p[rt][2] = fmaf(acc[rt][ct][2], u2, p[rt][2]);
            p[rt][3] = fmaf(acc[rt][ct][3], u3, p[rt][3]);
        }
    }
#pragma unroll
    for (int rt = 0; rt < 2; ++rt) {
#pragma unroll
        for (int off = 1; off <= 8; off <<= 1) {
            p[rt][0] += __shfl_xor(p[rt][0], off);
            p[rt][1] += __shfl_xor(p[rt][1], off);
            p[rt][2] += __shfl_xor(p[rt][2], off);
            p[rt][3] += __shfl_xor(p[rt][3], off);
        }
        if (l15 == 0)
            *(float4*)&scomb[wv][rt * 16 + hg * 4] =
                make_float4(p[rt][0], p[rt][1], p[rt][2], p[rt][3]);
    }
    __syncthreads();
    if (tid < 32) {
        const float s = ((scomb[0][tid] + scomb[1][tid]) + scomb[2][tid]) + scomb[3][tid];
        scores[(size_t)b * SS + row0 + tid] = s;
    }
}

// ---------------------------------------------------------------------------
// K2: fused softmax + weighted row-sum (attn ~one-hot: skip exact zeros).
// ---------------------------------------------------------------------------
__global__ __launch_bounds__(256) void fused_kernel(const float* __restrict__ x,
                                                    const float* __restrict__ scores,
                                                    float* __restrict__ y) {
    const int c = blockIdx.x;
    const int b = blockIdx.y;
    const int tid = threadIdx.x;
    const int lane = tid & 63;
    const int wid = tid >> 6;
    const float* sb = scores + (size_t)b * SS;

    float4 v[4];
    float m = -INFINITY;
#pragma unroll
    for (int i = 0; i < 4; ++i) {
        v[i] = *(const float4*)(sb + tid * 16 + i * 4);
        m = fmaxf(m, fmaxf(fmaxf(v[i].x, v[i].y), fmaxf(v[i].z, v[i].w)));
    }
#pragma unroll
    for (int off = 32; off >= 1; off >>= 1) m = fmaxf(m, __shfl_xor(m, off));
    __shared__ float redm[4];
    __shared__ float reds[4];
    __shared__ float a_s[64];
    if (lane == 0) redm[wid] = m;
    __syncthreads();
    const float M = fmaxf(fmaxf(redm[0], redm[1]), fmaxf(redm[2], redm[3]));

    float s = 0.f;
#pragma unroll
    for (int i = 0; i < 4; ++i) {
        s += expf(v[i].x - M);
        s += expf(v[i].y - M);
        s += expf(v[i].z - M);
        s += expf(v[i].w - M);
    }
#pragma unroll
    for (int off = 32; off >= 1; off >>= 1) s += __shfl_xor(s, off);
    if (lane == 0) reds[wid] = s;
    __syncthreads();
    const float S = ((reds[0] + reds[1]) + reds[2]) + reds[3];
    const float inv = 1.0f / S;

    if (tid < 64) a_s[tid] = expf(sb[c * 64 + tid] - M) * inv;
    __syncthreads();

    float accv = 0.f;
    for (int t = 0; t < 64; ++t) {
        const float a = a_s[t];
        if (a != 0.f)
            accv = fmaf(a, x[((size_t)(b * SS + c * 64 + t)) * DD + tid], accv);
    }
    atomicAdd(&y[b * DD + tid], accv);
}

// ---------------------------------------------------------------------------
// K3: out[b][o] += sum_{i in chunk} y[b][i] * W2[i][o].  grid (16, 4):
// 64 blocks spread the cold 256 KB W2 read across 64 CUs (was 4 -> latency
// bound). out zeroed in prep; fp32 atomics.
// ---------------------------------------------------------------------------
__global__ __launch_bounds__(256) void out_kernel(const float* __restrict__ y,
                                                  const float* __restrict__ W2,
                                                  float* __restrict__ out) {
    const int i0 = blockIdx.x * 16;
    const int b = blockIdx.y;
    const int o = threadIdx.x;
    __shared__ float y_s[16];
    if (o < 16) y_s[o] = y[b * DD + i0 + o];
    __syncthreads();
    float p = 0.f;
#pragma unroll
    for (int ii = 0; ii < 16; ++ii) p = fmaf(y_s[ii], W2[(size_t)(i0 + ii) * DD + o], p);
    atomicAdd(&out[b * DD + o], p);
}

// ---------------------------------------------------------------------------
extern "C" void kernel_launch(void* const* d_in, const int* in_sizes, int n_in,
                              void* d_out, int out_size, void* d_ws, size_t ws_size,
                              hipStream_t stream) {
    const float* x = (const float*)d_in[0];
    const float* W0 = (const float*)d_in[1];
    const float* W1 = (const float*)d_in[2];
    const float* W2 = (const float*)d_in[3];
    float* ws = (float*)d_ws;
    float* q = ws;                       // 1024 floats
    float* scores = ws + 1024;           // 16384 floats
    float* y = ws + 17408;               // 1024 floats
    ushort* wt = (ushort*)(ws + 18432);  // 2 planes x 65536 halves = 256 KB
    float* cs = ws + 116736;             // 128*4096*2 floats = 4 MB
    float* out = (float*)d_out;

    prep_kernel<<<dim3(2096), 256, 0, stream>>>(x, W0, W1, q, y, out, wt, cs);
    scores_mfma<<<dim3(512), 256, 0, stream>>>(x, wt, q, cs, scores);
    fused_kernel<<<dim3(64, BB), 256, 0, stream>>>(x, scores, y);
    out_kernel<<<dim3(16, BB), 256, 0, stream>>>(y, W2, out);
}